// Round 13
// baseline (294.952 us; speedup 1.0000x reference)
//
#include <hip/hip_runtime.h>
#include <hip/hip_bf16.h>

#define NTOT 1048576
#define NSEG 4096
#define HDIM 128
#define ODIM 256
#define BN   64
#define GRID1 1024
#define TPB  (NTOT / (BN * GRID1))   // 16 tiles per block

typedef __attribute__((ext_vector_type(8))) short bf16x8;
typedef __attribute__((ext_vector_type(4))) float f32x4;
typedef __attribute__((ext_vector_type(4))) unsigned int u32x4;

// HW packed f32->bf16 RNE (no builtin on gfx950)
__device__ __forceinline__ unsigned int cvt_pk(float lo, float hi) {
    unsigned int r;
    asm("v_cvt_pk_bf16_f32 %0, %1, %2" : "=v"(r) : "v"(lo), "v"(hi));
    return r;
}

// zero sumx (1M floats) + convert W1 (32768 f32 -> 16384 packed u32), one dispatch
__global__ void zero_convert(const float* __restrict__ W1, unsigned int* __restrict__ W1b,
                             float* __restrict__ sumx) {
    int gid = blockIdx.x * 256 + threadIdx.x;
    sumx[gid] = 0.0f;
    if (gid < (ODIM * HDIM / 2)) {
        float2 v = *(const float2*)(W1 + 2 * gid);
        W1b[gid] = cvt_pk(v.x, v.y);
    }
}

// Barrier-free stage1: no LDS, no __syncthreads, no manual waitcnt.
// Each wave independently streams its tiles' A-fragments global->regs
// (per mf-group: 8 x f32x4, 16 fully-covered 128B lines); the 4 waves of a
// block share each tile through L1/L2 (tile = 32KB), so HBM traffic stays
// 512 MB while waves free-run like a copy kernel (max MLP/TLP).
__global__ __launch_bounds__(256, 1)
void stage1(const float* __restrict__ x, const int* __restrict__ batch,
            const unsigned short* __restrict__ W1b, const float* __restrict__ b1,
            float* __restrict__ sumx) {
    const int t    = threadIdx.x;
    const int lane = t & 63;
    const int wv   = t >> 6;
    const int l15  = lane & 15;
    const int lhi  = (lane >> 4) & 3;

    // dtype probe: int64 little-endian => odd (high) words are 0
    const bool is64 = (batch[NTOT - 1] == 0);
    const long r0 = (long)blockIdx.x * (TPB * BN);

    // W1 B-fragments (64 VGPR, live whole kernel); wave wv owns cols [wv*64, wv*64+64)
    bf16x8 bfr[4][4];   // [nf][ks]
    #pragma unroll
    for (int nf = 0; nf < 4; ++nf)
        #pragma unroll
        for (int ks = 0; ks < 4; ++ks)
            bfr[nf][ks] = *(const bf16x8*)(W1b + (wv * 64 + nf * 16 + l15) * HDIM + ks * 32 + lhi * 8);
    float bias[4];
    #pragma unroll
    for (int nf = 0; nf < 4; ++nf) bias[nf] = b1[wv * 64 + nf * 16 + l15];

    for (int g = 0; g < TPB; ++g) {
        const long n0 = r0 + (long)g * BN;

        // per-lane segment id for this tile's 64 rows (registers, no LDS)
        int sv = batch[is64 ? 2 * (n0 + lane) : (n0 + lane)];
        int svp = __shfl(sv, lane > 0 ? lane - 1 : 0);
        unsigned long long bmask = __ballot(sv != svp);

        const float* xt = x + n0 * HDIM;

        f32x4 acc[4][4];
        #pragma unroll
        for (int nf = 0; nf < 4; ++nf) {
            const float bb = bias[nf];
            #pragma unroll
            for (int mf = 0; mf < 4; ++mf)
                acc[mf][nf] = (f32x4){bb, bb, bb, bb};
        }

        #pragma unroll
        for (int mf = 0; mf < 4; ++mf) {
            // A-fragments for rows mf*16..mf*16+16, full K: 8 x f32x4 per lane.
            // u+v per ks cover one full 128B line per row -> perfect coalescing.
            const float* rowp = xt + (mf * 16 + l15) * HDIM + lhi * 8;
            f32x4 u[4], v[4];
            #pragma unroll
            for (int ks = 0; ks < 4; ++ks) {
                u[ks] = *(const f32x4*)(rowp + ks * 32);
                v[ks] = *(const f32x4*)(rowp + ks * 32 + 4);
            }
            #pragma unroll
            for (int ks = 0; ks < 4; ++ks) {
                u32x4 w;
                w.x = cvt_pk(u[ks].x, u[ks].y); w.y = cvt_pk(u[ks].z, u[ks].w);
                w.z = cvt_pk(v[ks].x, v[ks].y); w.w = cvt_pk(v[ks].z, v[ks].w);
                bf16x8 af = __builtin_bit_cast(bf16x8, w);
                #pragma unroll
                for (int nf = 0; nf < 4; ++nf)
                    acc[mf][nf] = __builtin_amdgcn_mfma_f32_16x16x32_bf16(af, bfr[nf][ks], acc[mf][nf], 0, 0, 0);
            }
            // tanh(s) = 1 - 2/(1 + 2^(s*2*log2e))
            #pragma unroll
            for (int nf = 0; nf < 4; ++nf)
                #pragma unroll
                for (int r = 0; r < 4; ++r) {
                    float e = exp2f(acc[mf][nf][r] * 2.885390081777927f);
                    acc[mf][nf][r] = 1.0f - 2.0f * __builtin_amdgcn_rcpf(1.0f + e);
                }
        }

        // in-register segmented reduction (batch sorted); sid via shfl, no LDS
        int start = 0;
        unsigned long long rem = bmask;
        for (;;) {
            const int end = rem ? (int)__builtin_ctzll(rem) : BN;
            const int sid = __shfl(sv, start);
            float p0 = 0.f, p1 = 0.f, p2 = 0.f, p3 = 0.f;
            #pragma unroll
            for (int mf = 0; mf < 4; ++mf)
                #pragma unroll
                for (int r = 0; r < 4; ++r) {
                    int row = mf * 16 + lhi * 4 + r;
                    float w = ((unsigned)(row - start) < (unsigned)(end - start)) ? 1.0f : 0.0f;
                    p0 = fmaf(w, acc[mf][0][r], p0);
                    p1 = fmaf(w, acc[mf][1][r], p1);
                    p2 = fmaf(w, acc[mf][2][r], p2);
                    p3 = fmaf(w, acc[mf][3][r], p3);
                }
            p0 += __shfl_xor(p0, 16); p0 += __shfl_xor(p0, 32);
            p1 += __shfl_xor(p1, 16); p1 += __shfl_xor(p1, 32);
            p2 += __shfl_xor(p2, 16); p2 += __shfl_xor(p2, 32);
            p3 += __shfl_xor(p3, 16); p3 += __shfl_xor(p3, 32);
            if (lhi == 0) {
                float* base = sumx + (long)sid * ODIM + wv * 64 + l15;
                atomicAdd(base +  0, p0);
                atomicAdd(base + 16, p1);
                atomicAdd(base + 32, p2);
                atomicAdd(base + 48, p3);
            }
            if (rem == 0) break;
            start = end;
            rem &= rem - 1;
        }
    }
}

// y[g][h] = b2[h] + sum_o sumx[g][o] * W2[h][o]   (fp32, 268 MFLOP)
__global__ __launch_bounds__(256)
void stage2(const float* __restrict__ sumx, const float* __restrict__ W2,
            const float* __restrict__ b2, float* __restrict__ y) {
    __shared__ float sx[16 * 256];
    const int t = threadIdx.x;
    const long g0 = (long)blockIdx.x * 16;
    #pragma unroll
    for (int i = 0; i < 16; ++i)
        sx[i * 256 + t] = sumx[(g0 + i) * 256 + t];
    __syncthreads();
    const int h = t & 127;
    const int gl0 = (t >> 7) * 8;
    float acc[8] = {0, 0, 0, 0, 0, 0, 0, 0};
    const float* w = W2 + h * 256;
    for (int o4 = 0; o4 < 64; ++o4) {
        float4 wvv = *(const float4*)(w + o4 * 4);
        #pragma unroll
        for (int gl = 0; gl < 8; ++gl) {
            const float* sr = &sx[(gl0 + gl) * 256 + o4 * 4];
            acc[gl] += sr[0] * wvv.x + sr[1] * wvv.y + sr[2] * wvv.z + sr[3] * wvv.w;
        }
    }
    float bb = b2[h];
    #pragma unroll
    for (int gl = 0; gl < 8; ++gl)
        y[(g0 + gl0 + gl) * 128 + h] = acc[gl] + bb;
}

extern "C" void kernel_launch(void* const* d_in, const int* in_sizes, int n_in,
                              void* d_out, int out_size, void* d_ws, size_t ws_size,
                              hipStream_t stream) {
    const float* x   = (const float*)d_in[0];
    const int* batch = (const int*)d_in[1];
    const float* W1  = (const float*)d_in[2];
    const float* b1  = (const float*)d_in[3];
    const float* W2  = (const float*)d_in[4];
    const float* b2  = (const float*)d_in[5];
    float* y = (float*)d_out;

    float* sumx = (float*)d_ws;                                                     // 4 MB
    unsigned short* W1b = (unsigned short*)((char*)d_ws + (size_t)NSEG * ODIM * 4); // 64 KB

    zero_convert<<<dim3(NSEG), dim3(256), 0, stream>>>(W1, (unsigned int*)W1b, sumx);
    stage1<<<dim3(GRID1), dim3(256), 0, stream>>>(x, batch, W1b, b1, sumx);
    stage2<<<dim3(NSEG / 16), dim3(256), 0, stream>>>(sumx, W2, b2, y);
}